// Round 9
// baseline (487.390 us; speedup 1.0000x reference)
//
#include <hip/hip_runtime.h>
#include <math.h>

// ---------------------------------------------------------------------------
// B=256 images, N=256 tokens/image. L1: Cu=12,d=16(dh=4),r=16 -> 64ch.
// L2: Cu=64,d=32(dh=8),r=32 -> 128ch. shuffle(L1) o unshuffle(L2) == identity.
// R9: k7 BK 64 -> 256. __syncthreads drains vmcnt(0) (guide §5), so every
// K-iteration exposed a full HBM latency on the staged B loads; 4x fewer
// iterations = 4x fewer drains, same bytes. Everything else = R8 (verified).
// Selection-critical path (q/k/t2) stays exact fp32.
// ---------------------------------------------------------------------------

typedef float floatx4 __attribute__((ext_vector_type(4)));
typedef __bf16 bf16x8 __attribute__((ext_vector_type(8)));

// ---- workspace layout (float offsets), peak 62.9 MB ----
static constexpr size_t OQ1 = 0;          // [65536,16] ..1048576
static constexpr size_t OK1 = 1048576;    // ..2097152
static constexpr size_t OV1 = 2097152;    // ..3145728
static constexpr size_t OL1 = 3145728;    // ..4194304
static constexpr size_t OA1 = 4194304;    // ..5242880
static constexpr size_t OT2 = 5242880;    // [65536,64] ..9437184
static constexpr size_t OQ2 = 0;          // [65536,32] ..2097152 (q1/k1 dead)
static constexpr size_t OK2 = 2097152;    // ..4194304 (v1/loc1 dead after proj1)
static constexpr size_t OV2 = 9437184;    // ..11534336
static constexpr size_t OL2 = 11534336;   // ..13631488
static constexpr size_t OA2 = 13631488;   // ..15728640
static constexpr size_t OH  = 5242880;    // h bf16 [256,32768] = 4194304 floats ..9437184 (t2 dead)
static constexpr size_t OPART = 9437184;  // [16][256][1024] ..13631488 (v2/loc2 dead at k7)

__device__ inline bf16x8 pack8(const float* f) {
  bf16x8 v;
#pragma unroll
  for (int i = 0; i < 8; ++i) v[i] = (__bf16)f[i];
  return v;
}

// ---------------- K1: pixel_unshuffle + q/k/v/local projections, layer 1 ----
__global__ __launch_bounds__(256) void k1_qkv1(
    const float* __restrict__ x, const float* __restrict__ w1q,
    const float* __restrict__ w1k, const float* __restrict__ w1v,
    const float* __restrict__ w1c, const float* __restrict__ b1c,
    float* __restrict__ q1, float* __restrict__ k1,
    float* __restrict__ v1, float* __restrict__ loc1)
{
  const int tid = threadIdx.x;
  const int slot = tid >> 6;
  const int lane = tid & 63;
  const int tok = blockIdx.x * 4 + slot;   // b*256+n
  const int b = tok >> 8, n = tok & 255;
  const int i = n >> 4, j = n & 15;
  __shared__ float ts[4][12];
  if (lane < 12) {
    const int c0 = lane >> 2, si = (lane >> 1) & 1, sj = lane & 1;
    ts[slot][lane] = x[((size_t)(b * 3 + c0) * 32 + 2 * i + si) * 32 + 2 * j + sj];
  }
  __syncthreads();
  const int mat = lane >> 4, col = lane & 15;
  const float* W = (mat == 0) ? w1q : (mat == 1) ? w1k : (mat == 2) ? w1v : w1c;
  float acc = 0.f;
#pragma unroll
  for (int c = 0; c < 12; ++c) acc += ts[slot][c] * W[c * 16 + col];
  const size_t o = (size_t)tok * 16 + col;
  if (mat == 0) q1[o] = acc;
  else if (mat == 1) k1[o] = acc;
  else if (mat == 2) v1[o] = acc;
  else loc1[o] = fmaxf(acc + b1c[col], 0.f);
}

// ---------------- attention select+aggregate: 4-way candidate split --------
// 256 thr / 64 tokens per block; thread = (token tok, quarter qt).
// Wave qt scans candidates qt*64..qt*64+63 for its token -> local top-9
// (strict >, ascending m == lax.top_k tie semantics within the quarter).
// Wave 0 merges the 4 sorted lists streamed in quarter order -> final 9.
// Phases 2/3: thread handles head qt of its token; gathers from global (L2).
template <int D, int DH, int NH>
__global__ __launch_bounds__(256) void attn_sel(
    const float* __restrict__ q, const float* __restrict__ k,
    const float* __restrict__ v, float* __restrict__ agg)
{
  const int blk = blockIdx.x;
  const int b = blk >> 2;              // image
  const int t0 = (blk & 3) * 64;       // token base within image
  const int tid = threadIdx.x;
  const int tok = tid & 63;            // local token
  const int qt = tid >> 6;             // candidate quarter == wave == head
  __shared__ float ks[256 * D];
  __shared__ float mvS[4 * 576];       // [qq][tok*9+r]
  __shared__ int   miS[4 * 576];
  __shared__ int   selS[576];          // [tok*9+kk]
  const size_t base = (size_t)b * (256 * D);
  for (int idx = tid * 4; idx < 256 * D; idx += 1024)
    *(float4*)&ks[idx] = *(const float4*)&k[base + idx];
  float qr[D];
  {
    const float4* qrow = (const float4*)&q[base + (size_t)(t0 + tok) * D];
#pragma unroll
    for (int c4 = 0; c4 < D / 4; ++c4) {
      const float4 qv = qrow[c4];
      qr[4 * c4 + 0] = qv.x; qr[4 * c4 + 1] = qv.y;
      qr[4 * c4 + 2] = qv.z; qr[4 * c4 + 3] = qv.w;
    }
  }
  __syncthreads();

  float topv[9];
  int topi[9];
#pragma unroll
  for (int r = 0; r < 9; ++r) { topv[r] = -__builtin_inff(); topi[r] = 0; }

#pragma unroll 2
  for (int j = 0; j < 64; ++j) {
    const int m = qt * 64 + j;
    const float4* kr = (const float4*)&ks[m * D];
    float p0 = 0.f, p1 = 0.f, p2 = 0.f, p3 = 0.f;
#pragma unroll
    for (int g = 0; g < D / 16; ++g) {
      const float4 ka = kr[g * 4 + 0], kb = kr[g * 4 + 1];
      const float4 kc = kr[g * 4 + 2], kd = kr[g * 4 + 3];
      p0 += qr[g*16+ 0]*ka.x + qr[g*16+ 1]*ka.y + qr[g*16+ 2]*ka.z + qr[g*16+ 3]*ka.w;
      p1 += qr[g*16+ 4]*kb.x + qr[g*16+ 5]*kb.y + qr[g*16+ 6]*kb.z + qr[g*16+ 7]*kb.w;
      p2 += qr[g*16+ 8]*kc.x + qr[g*16+ 9]*kc.y + qr[g*16+10]*kc.z + qr[g*16+11]*kc.w;
      p3 += qr[g*16+12]*kd.x + qr[g*16+13]*kd.y + qr[g*16+14]*kd.z + qr[g*16+15]*kd.w;
    }
    const float s = (p0 + p1) + (p2 + p3);
    bool ci = s > topv[8];
#pragma unroll
    for (int i = 8; i >= 1; --i) {
      const bool cim1 = s > topv[i - 1];
      topv[i] = ci ? (cim1 ? topv[i - 1] : s) : topv[i];
      topi[i] = ci ? (cim1 ? topi[i - 1] : m) : topi[i];
      ci = cim1;
    }
    topv[0] = ci ? s : topv[0];
    topi[0] = ci ? m : topi[0];
  }
#pragma unroll
  for (int r = 0; r < 9; ++r) {
    mvS[qt * 576 + tok * 9 + r] = topv[r];
    miS[qt * 576 + tok * 9 + r] = topi[r];
  }
  __syncthreads();
  if (qt == 0) {   // wave 0 merges 36 -> 9 for its token
    float fv[9];
    int fi[9];
#pragma unroll
    for (int r = 0; r < 9; ++r) { fv[r] = -__builtin_inff(); fi[r] = 0; }
#pragma unroll
    for (int qq = 0; qq < 4; ++qq)
#pragma unroll
      for (int r = 0; r < 9; ++r) {
        const float s = mvS[qq * 576 + tok * 9 + r];
        const int ix = miS[qq * 576 + tok * 9 + r];
        bool ci = s > fv[8];
#pragma unroll
        for (int i = 8; i >= 1; --i) {
          const bool cim1 = s > fv[i - 1];
          fv[i] = ci ? (cim1 ? fv[i - 1] : s) : fv[i];
          fi[i] = ci ? (cim1 ? fi[i - 1] : ix) : fi[i];
          ci = cim1;
        }
        fv[0] = ci ? s : fv[0];
        fi[0] = ci ? ix : fi[0];
      }
#pragma unroll
    for (int r = 0; r < 9; ++r) selS[tok * 9 + r] = fi[r];
  }
  __syncthreads();

  // phases 2/3: this thread handles head hh = qt of token tok.
  const int hh = qt;
  const float scale = (DH == 4) ? 0.5f : 0.35355339059327373f;
  int sel9[9];
#pragma unroll
  for (int kk = 0; kk < 9; ++kk) sel9[kk] = selS[tok * 9 + kk];
  float lg9[9];
#pragma unroll
  for (int kk = 0; kk < 9; ++kk) {
    const float4* kr = (const float4*)&k[base + (size_t)sel9[kk] * D + hh * DH];
    float s = 0.f;
#pragma unroll
    for (int u = 0; u < DH / 4; ++u) {
      const float4 ka = kr[u];
      s += qr[hh*DH + u*4 + 0]*ka.x + qr[hh*DH + u*4 + 1]*ka.y +
           qr[hh*DH + u*4 + 2]*ka.z + qr[hh*DH + u*4 + 3]*ka.w;
    }
    lg9[kk] = s * scale;
  }
  float mx = lg9[0];
#pragma unroll
  for (int kk = 1; kk < 9; ++kk) mx = fmaxf(mx, lg9[kk]);
  float sum = 0.f;
#pragma unroll
  for (int kk = 0; kk < 9; ++kk) { lg9[kk] = __expf(lg9[kk] - mx); sum += lg9[kk]; }
  const float inv = 1.f / sum;
  float oacc[DH];
#pragma unroll
  for (int c = 0; c < DH; ++c) oacc[c] = 0.f;
#pragma unroll
  for (int kk = 0; kk < 9; ++kk) {
    const float4* vr = (const float4*)&v[base + (size_t)sel9[kk] * D + hh * DH];
    const float w = lg9[kk] * inv;
#pragma unroll
    for (int u = 0; u < DH / 4; ++u) {
      const float4 va = vr[u];
      oacc[u*4+0] += w * va.x; oacc[u*4+1] += w * va.y;
      oacc[u*4+2] += w * va.z; oacc[u*4+3] += w * va.w;
    }
  }
  float* o = &agg[base + (size_t)(t0 + tok) * D + hh * DH];
#pragma unroll
  for (int u = 0; u < DH / 4; ++u)
    *(float4*)&o[u * 4] = make_float4(oacc[u*4], oacc[u*4+1], oacc[u*4+2], oacc[u*4+3]);
}

// ---------------- proj1: t2 = [loc1|agg1] @ W1o + b1o, exact fp32 ----------
__global__ __launch_bounds__(256) void proj1(
    const float* __restrict__ loc1, const float* __restrict__ agg1,
    const float* __restrict__ w1o, const float* __restrict__ b1o,
    float* __restrict__ t2)
{
  const int tid = threadIdx.x;
  const int tok = blockIdx.x * 256 + tid;
  __shared__ float wS[32 * 64];   // 8 KB
  __shared__ float bS[64];
  for (int idx = tid * 4; idx < 2048; idx += 1024)
    *(float4*)&wS[idx] = *(const float4*)&w1o[idx];
  if (tid < 64) bS[tid] = b1o[tid];
  float cat[32];
#pragma unroll
  for (int c4 = 0; c4 < 4; ++c4) {
    const float4 l4 = *(const float4*)&loc1[(size_t)tok * 16 + c4 * 4];
    cat[4*c4+0] = l4.x; cat[4*c4+1] = l4.y; cat[4*c4+2] = l4.z; cat[4*c4+3] = l4.w;
    const float4 a4 = *(const float4*)&agg1[(size_t)tok * 16 + c4 * 4];
    cat[16+4*c4+0] = a4.x; cat[16+4*c4+1] = a4.y; cat[16+4*c4+2] = a4.z; cat[16+4*c4+3] = a4.w;
  }
  __syncthreads();
  float acc[64];
#pragma unroll
  for (int o = 0; o < 64; ++o) acc[o] = 0.f;
#pragma unroll 4
  for (int c = 0; c < 32; ++c) {
    const float cv = cat[c];
#pragma unroll
    for (int o4 = 0; o4 < 16; ++o4) {
      const float4 w4 = *(const float4*)&wS[c * 64 + o4 * 4];
      acc[o4*4+0] += cv * w4.x; acc[o4*4+1] += cv * w4.y;
      acc[o4*4+2] += cv * w4.z; acc[o4*4+3] += cv * w4.w;
    }
  }
  float* dst = t2 + (size_t)tok * 64;
#pragma unroll
  for (int o4 = 0; o4 < 16; ++o4)
    *(float4*)&dst[o4 * 4] = make_float4(acc[o4*4] + bS[o4*4], acc[o4*4+1] + bS[o4*4+1],
                                         acc[o4*4+2] + bS[o4*4+2], acc[o4*4+3] + bS[o4*4+3]);
}

// ---------------- K4: layer-2 q/k/v/local projections, exact fp32 ----------
__global__ __launch_bounds__(256) void k4_qkv2(
    const float* __restrict__ t2, const float* __restrict__ w2q,
    const float* __restrict__ w2k, const float* __restrict__ w2v,
    const float* __restrict__ w2c, const float* __restrict__ b2c,
    float* __restrict__ q2, float* __restrict__ k2,
    float* __restrict__ v2, float* __restrict__ loc2)
{
  const int blk = blockIdx.x;       // 1024 blocks x 64 tokens
  const int tid = threadIdx.x;
  __shared__ float t2S[64 * 68];    // 17.4 KB
  __shared__ float wS[4 * 2312];    // 37 KB
  __shared__ float bS[32];
  for (int idx = tid * 4; idx < 4096; idx += 1024) {
    const float4 vv = *(const float4*)&t2[(size_t)blk * 4096 + idx];
    *(float4*)&t2S[(idx >> 6) * 68 + (idx & 63)] = vv;
  }
  for (int idx = tid * 4; idx < 2048; idx += 1024) {
    const int c = idx >> 5, col = idx & 31;
    *(float4*)&wS[0 * 2312 + c * 36 + col] = *(const float4*)&w2q[idx];
    *(float4*)&wS[1 * 2312 + c * 36 + col] = *(const float4*)&w2k[idx];
    *(float4*)&wS[2 * 2312 + c * 36 + col] = *(const float4*)&w2v[idx];
    *(float4*)&wS[3 * 2312 + c * 36 + col] = *(const float4*)&w2c[idx];
  }
  if (tid < 32) bS[tid] = b2c[tid];
  __syncthreads();
  const int tq = tid >> 2, mat = tid & 3;
  const float* wm = &wS[mat * 2312];
  float acc[32];
#pragma unroll
  for (int e = 0; e < 32; ++e) acc[e] = 0.f;
#pragma unroll 4
  for (int c = 0; c < 64; ++c) {
    const float tv = t2S[tq * 68 + c];
#pragma unroll
    for (int o4 = 0; o4 < 8; ++o4) {
      const float4 w4 = *(const float4*)&wm[c * 36 + o4 * 4];
      acc[o4*4+0] += tv * w4.x; acc[o4*4+1] += tv * w4.y;
      acc[o4*4+2] += tv * w4.z; acc[o4*4+3] += tv * w4.w;
    }
  }
  if (mat == 3) {
#pragma unroll
    for (int e = 0; e < 32; ++e) acc[e] = fmaxf(acc[e] + bS[e], 0.f);
  }
  float* dst = (mat == 0) ? q2 : (mat == 1) ? k2 : (mat == 2) ? v2 : loc2;
  float* drow = dst + (size_t)(blk * 64 + tq) * 32;
#pragma unroll
  for (int o4 = 0; o4 < 8; ++o4)
    *(float4*)&drow[o4 * 4] = make_float4(acc[o4*4], acc[o4*4+1], acc[o4*4+2], acc[o4*4+3]);
}

// ---------------- proj2h: h = [loc2|agg2] @ W2o + b2o (bf16 MFMA) ----------
__global__ __launch_bounds__(256) void proj2h(
    const float* __restrict__ loc2, const float* __restrict__ agg2,
    const float* __restrict__ w2o, const float* __restrict__ b2o,
    __bf16* __restrict__ h)
{
  const int b = blockIdx.x;
  const int t = threadIdx.x;
  __shared__ __bf16 catB[256 * 72];   // 36.9 KB
  __shared__ __bf16 wB[128 * 72];     // 18.4 KB  [n][k]
  {  // stage W2o transposed to bf16 [n][k]
    const int n = t >> 1, khalf = t & 1;
    float wv[32];
#pragma unroll
    for (int j = 0; j < 32; ++j) wv[j] = w2o[(size_t)(khalf * 32 + j) * 128 + n];
#pragma unroll
    for (int j8 = 0; j8 < 4; ++j8)
      *(bf16x8*)&wB[n * 72 + khalf * 32 + j8 * 8] = pack8(&wv[j8 * 8]);
  }
  {  // stage cat row (loc2 | agg2) as bf16
    float lv[32];
#pragma unroll
    for (int c4 = 0; c4 < 8; ++c4) {
      const float4 x4 = *(const float4*)&loc2[(size_t)(b * 256 + t) * 32 + c4 * 4];
      lv[4*c4+0] = x4.x; lv[4*c4+1] = x4.y; lv[4*c4+2] = x4.z; lv[4*c4+3] = x4.w;
    }
#pragma unroll
    for (int c8 = 0; c8 < 4; ++c8)
      *(bf16x8*)&catB[t * 72 + c8 * 8] = pack8(&lv[c8 * 8]);
#pragma unroll
    for (int c4 = 0; c4 < 8; ++c4) {
      const float4 x4 = *(const float4*)&agg2[(size_t)(b * 256 + t) * 32 + c4 * 4];
      lv[4*c4+0] = x4.x; lv[4*c4+1] = x4.y; lv[4*c4+2] = x4.z; lv[4*c4+3] = x4.w;
    }
#pragma unroll
    for (int c8 = 0; c8 < 4; ++c8)
      *(bf16x8*)&catB[t * 72 + 32 + c8 * 8] = pack8(&lv[c8 * 8]);
  }
  __syncthreads();
  const int w = t >> 6, lane = t & 63, qd = lane >> 4, mcol = lane & 15;
#pragma unroll
  for (int nc = 0; nc < 2; ++nc) {
    floatx4 acc[4][4];
#pragma unroll
    for (int mi = 0; mi < 4; ++mi)
#pragma unroll
      for (int nj = 0; nj < 4; ++nj) acc[mi][nj] = (floatx4)0.f;
#pragma unroll
    for (int s = 0; s < 2; ++s) {
      bf16x8 af[4], bf[4];
#pragma unroll
      for (int mi = 0; mi < 4; ++mi)
        af[mi] = *(const bf16x8*)&catB[(w * 64 + mi * 16 + mcol) * 72 + s * 32 + qd * 8];
#pragma unroll
      for (int nj = 0; nj < 4; ++nj)
        bf[nj] = *(const bf16x8*)&wB[((nc * 4 + nj) * 16 + mcol) * 72 + s * 32 + qd * 8];
#pragma unroll
      for (int mi = 0; mi < 4; ++mi)
#pragma unroll
        for (int nj = 0; nj < 4; ++nj)
          acc[mi][nj] = __builtin_amdgcn_mfma_f32_16x16x32_bf16(af[mi], bf[nj], acc[mi][nj], 0, 0, 0);
    }
#pragma unroll
    for (int mi = 0; mi < 4; ++mi)
#pragma unroll
      for (int nj = 0; nj < 4; ++nj) {
        const int ch = (nc * 4 + nj) * 16 + mcol;
        const float bb = b2o[ch];
        const int cc = ch >> 2, si = (ch >> 1) & 1, sj = ch & 1;
#pragma unroll
        for (int r = 0; r < 4; ++r) {
          const int tok = w * 64 + mi * 16 + qd * 4 + r;
          const int i = tok >> 4, j = tok & 15;
          h[(size_t)b * 32768 + cc * 1024 + (2 * i + si) * 32 + (2 * j + sj)] =
              (__bf16)(acc[mi][nj][r] + bb);
        }
      }
  }
}

// ---------------- K7: fc1 GEMM bf16 MFMA, BK=256 ---------------------------
// grid 512: bn (32 N-tiles of 32) x bk (16 K-chunks of 2048); 8 iterations
// of BK=256 per block. __syncthreads drains vmcnt(0), so fewer/bigger
// iterations amortize the exposed HBM latency (32 drains -> 8 per block).
// Within an iteration the compiler software-pipelines A-loads with MFMA.
__global__ __launch_bounds__(256) void k7_fc1_gemm(
    const __bf16* __restrict__ A,  // h bf16 [256, 32768]
    const float* __restrict__ Bw,  // fc1_w fp32 [32768, 1024]
    float* __restrict__ part)      // [16][256][1024]
{
  __shared__ __bf16 Bs[32 * 264];  // [n][k] 16.9 KB, pad 264
  const int bn = blockIdx.x & 31;
  const int bk = blockIdx.x >> 5;
  const int n0 = bn * 32, k0 = bk * 2048;
  const int tid = threadIdx.x;
  const int n = tid & 31;          // staging column
  const int kg = tid >> 5;         // staging k-group (8 groups of 32)
  const int w = tid >> 6, lane = tid & 63;
  const int qd = lane >> 4, mcol = lane & 15;
  floatx4 acc[4][2];
#pragma unroll
  for (int mi = 0; mi < 4; ++mi)
#pragma unroll
    for (int ni = 0; ni < 2; ++ni) acc[mi][ni] = (floatx4)0.f;

  for (int it = 0; it < 8; ++it) {
    const int kk0 = k0 + it * 256;
    float bv[32];
    const float* bp = Bw + (size_t)(kk0 + kg * 32) * 1024 + n0 + n;
#pragma unroll
    for (int j = 0; j < 32; ++j) bv[j] = bp[(size_t)j * 1024];
    __syncthreads();   // previous iteration's Bs reads complete
#pragma unroll
    for (int j8 = 0; j8 < 4; ++j8)
      *(bf16x8*)&Bs[n * 264 + kg * 32 + j8 * 8] = pack8(&bv[j8 * 8]);
    __syncthreads();
#pragma unroll
    for (int s = 0; s < 8; ++s) {
      bf16x8 af[4], bf[2];
#pragma unroll
      for (int mi = 0; mi < 4; ++mi)
        af[mi] = *(const bf16x8*)(A + (size_t)(w * 64 + mi * 16 + mcol) * 32768
                                     + kk0 + s * 32 + qd * 8);
#pragma unroll
      for (int ni = 0; ni < 2; ++ni)
        bf[ni] = *(const bf16x8*)&Bs[(ni * 16 + mcol) * 264 + s * 32 + qd * 8];
#pragma unroll
      for (int mi = 0; mi < 4; ++mi)
#pragma unroll
        for (int ni = 0; ni < 2; ++ni)
          acc[mi][ni] = __builtin_amdgcn_mfma_f32_16x16x32_bf16(af[mi], bf[ni], acc[mi][ni], 0, 0, 0);
    }
  }
  float* P = part + (size_t)bk * 262144;
#pragma unroll
  for (int mi = 0; mi < 4; ++mi)
#pragma unroll
    for (int ni = 0; ni < 2; ++ni) {
      const int col = n0 + ni * 16 + mcol;
#pragma unroll
      for (int r = 0; r < 4; ++r) {
        const int row = w * 64 + mi * 16 + qd * 4 + r;
        P[(size_t)row * 1024 + col] = acc[mi][ni][r];
      }
    }
}

// ---------------- K7c+K8: splitK reduce + bias/relu + fc2 ------------------
__global__ __launch_bounds__(256) void k7c8_fc2(
    const float* __restrict__ part, const float* __restrict__ fc1b,
    const float* __restrict__ w2, const float* __restrict__ b2,
    float* __restrict__ out)
{
  const int b = blockIdx.x, t = threadIdx.x;
  const int col4 = t * 4;
  float4 s = make_float4(0.f, 0.f, 0.f, 0.f);
#pragma unroll
  for (int p = 0; p < 16; ++p) {
    const float4 x4 = *(const float4*)&part[(size_t)p * 262144 + (size_t)b * 1024 + col4];
    s.x += x4.x; s.y += x4.y; s.z += x4.z; s.w += x4.w;
  }
  const float4 bb = *(const float4*)&fc1b[col4];
  float a[4] = {fmaxf(s.x + bb.x, 0.f), fmaxf(s.y + bb.y, 0.f),
                fmaxf(s.z + bb.z, 0.f), fmaxf(s.w + bb.w, 0.f)};
  float acc[10];
#pragma unroll
  for (int o = 0; o < 10; ++o) acc[o] = 0.f;
#pragma unroll
  for (int i = 0; i < 4; ++i) {
    const float* wr = w2 + (size_t)(col4 + i) * 10;
#pragma unroll
    for (int o = 0; o < 10; ++o) acc[o] += a[i] * wr[o];
  }
  __shared__ float red[256][10];
#pragma unroll
  for (int o = 0; o < 10; ++o) red[t][o] = acc[o];
  __syncthreads();
  for (int st = 128; st > 0; st >>= 1) {
    if (t < st) {
#pragma unroll
      for (int o = 0; o < 10; ++o) red[t][o] += red[t + st][o];
    }
    __syncthreads();
  }
  if (t < 10) out[b * 10 + t] = red[0][t] + b2[t];
}

// ---------------------------------------------------------------------------
extern "C" void kernel_launch(void* const* d_in, const int* in_sizes, int n_in,
                              void* d_out, int out_size, void* d_ws, size_t ws_size,
                              hipStream_t stream)
{
  const float* x    = (const float*)d_in[0];
  const float* w1c  = (const float*)d_in[1];
  const float* b1c  = (const float*)d_in[2];
  const float* w1q  = (const float*)d_in[3];
  const float* w1k  = (const float*)d_in[4];
  const float* w1v  = (const float*)d_in[5];
  const float* w1o  = (const float*)d_in[6];
  const float* b1o  = (const float*)d_in[7];
  const float* w2c  = (const float*)d_in[8];
  const float* b2c  = (const float*)d_in[9];
  const float* w2q  = (const float*)d_in[10];
  const float* w2k  = (const float*)d_in[11];
  const float* w2v  = (const float*)d_in[12];
  const float* w2o  = (const float*)d_in[13];
  const float* b2o  = (const float*)d_in[14];
  const float* fc1w = (const float*)d_in[15];
  const float* fc1b = (const float*)d_in[16];
  const float* fc2w = (const float*)d_in[17];
  const float* fc2b = (const float*)d_in[18];
  float* out = (float*)d_out;
  float* ws = (float*)d_ws;

  float* q1   = ws + OQ1;
  float* k1   = ws + OK1;
  float* v1   = ws + OV1;
  float* loc1 = ws + OL1;
  float* agg1 = ws + OA1;
  float* t2   = ws + OT2;
  float* q2   = ws + OQ2;
  float* k2   = ws + OK2;
  float* v2   = ws + OV2;
  float* loc2 = ws + OL2;
  float* agg2 = ws + OA2;
  __bf16* h   = (__bf16*)(ws + OH);
  float* prt  = ws + OPART;

  k1_qkv1<<<16384, 256, 0, stream>>>(x, w1q, w1k, w1v, w1c, b1c, q1, k1, v1, loc1);
  attn_sel<16, 4, 4><<<1024, 256, 0, stream>>>(q1, k1, v1, agg1);
  proj1<<<256, 256, 0, stream>>>(loc1, agg1, w1o, b1o, t2);
  k4_qkv2<<<1024, 256, 0, stream>>>(t2, w2q, w2k, w2v, w2c, b2c, q2, k2, v2, loc2);
  attn_sel<32, 8, 4><<<1024, 256, 0, stream>>>(q2, k2, v2, agg2);
  proj2h<<<256, 256, 0, stream>>>(loc2, agg2, w2o, b2o, h);
  k7_fc1_gemm<<<512, 256, 0, stream>>>(h, fc1w, prt);
  k7c8_fc2<<<256, 256, 0, stream>>>(prt, fc1b, fc2w, fc2b, out);
}

// Round 10
// 475.010 us; speedup vs baseline: 1.0261x; 1.0261x over previous
//
#include <hip/hip_runtime.h>
#include <math.h>

// ---------------------------------------------------------------------------
// B=256 images, N=256 tokens/image. L1: Cu=12,d=16(dh=4),r=16 -> 64ch.
// L2: Cu=64,d=32(dh=8),r=32 -> 128ch. shuffle(L1) o unshuffle(L2) == identity.
// R10: attn_sel LDS union — merge arrays (20.7 KB) alias ks (scan-only
// lifetime; phases 2/3 gather K/V from global since R3). Block LDS
// 53.8->32 KB (L2) / 37->20.7 KB (L1): occupancy 2 -> 5/7 blocks per CU.
// One extra barrier after the scan makes aliasing safe. Only attn changed.
// Selection-critical path (q/k/t2) stays exact fp32.
// ---------------------------------------------------------------------------

typedef float floatx4 __attribute__((ext_vector_type(4)));
typedef __bf16 bf16x8 __attribute__((ext_vector_type(8)));

// ---- workspace layout (float offsets), peak 62.9 MB ----
static constexpr size_t OQ1 = 0;          // [65536,16] ..1048576
static constexpr size_t OK1 = 1048576;    // ..2097152
static constexpr size_t OV1 = 2097152;    // ..3145728
static constexpr size_t OL1 = 3145728;    // ..4194304
static constexpr size_t OA1 = 4194304;    // ..5242880
static constexpr size_t OT2 = 5242880;    // [65536,64] ..9437184
static constexpr size_t OQ2 = 0;          // [65536,32] ..2097152 (q1/k1 dead)
static constexpr size_t OK2 = 2097152;    // ..4194304 (v1/loc1 dead after proj1)
static constexpr size_t OV2 = 9437184;    // ..11534336
static constexpr size_t OL2 = 11534336;   // ..13631488
static constexpr size_t OA2 = 13631488;   // ..15728640
static constexpr size_t OH  = 5242880;    // h bf16 [256,32768] = 4194304 floats ..9437184 (t2 dead)
static constexpr size_t OPART = 9437184;  // [16][256][1024] ..13631488 (v2/loc2 dead at k7)

__device__ inline bf16x8 pack8(const float* f) {
  bf16x8 v;
#pragma unroll
  for (int i = 0; i < 8; ++i) v[i] = (__bf16)f[i];
  return v;
}

// ---------------- K1: pixel_unshuffle + q/k/v/local projections, layer 1 ----
__global__ __launch_bounds__(256) void k1_qkv1(
    const float* __restrict__ x, const float* __restrict__ w1q,
    const float* __restrict__ w1k, const float* __restrict__ w1v,
    const float* __restrict__ w1c, const float* __restrict__ b1c,
    float* __restrict__ q1, float* __restrict__ k1,
    float* __restrict__ v1, float* __restrict__ loc1)
{
  const int tid = threadIdx.x;
  const int slot = tid >> 6;
  const int lane = tid & 63;
  const int tok = blockIdx.x * 4 + slot;   // b*256+n
  const int b = tok >> 8, n = tok & 255;
  const int i = n >> 4, j = n & 15;
  __shared__ float ts[4][12];
  if (lane < 12) {
    const int c0 = lane >> 2, si = (lane >> 1) & 1, sj = lane & 1;
    ts[slot][lane] = x[((size_t)(b * 3 + c0) * 32 + 2 * i + si) * 32 + 2 * j + sj];
  }
  __syncthreads();
  const int mat = lane >> 4, col = lane & 15;
  const float* W = (mat == 0) ? w1q : (mat == 1) ? w1k : (mat == 2) ? w1v : w1c;
  float acc = 0.f;
#pragma unroll
  for (int c = 0; c < 12; ++c) acc += ts[slot][c] * W[c * 16 + col];
  const size_t o = (size_t)tok * 16 + col;
  if (mat == 0) q1[o] = acc;
  else if (mat == 1) k1[o] = acc;
  else if (mat == 2) v1[o] = acc;
  else loc1[o] = fmaxf(acc + b1c[col], 0.f);
}

// ---------------- attention select+aggregate: 4-way candidate split --------
// 256 thr / 64 tokens per block; thread = (token tok, quarter qt).
// Wave qt scans candidates qt*64..qt*64+63 -> local top-9 (strict >,
// ascending m == lax.top_k tie semantics). Wave 0 merges the 4 sorted lists
// in quarter order -> final 9. Phases 2/3: thread = head qt of its token,
// K/V rows gathered from global (L2).
// LDS: merge arrays ALIAS ks (disjoint lifetimes; barrier after scan).
template <int D, int DH, int NH>
__global__ __launch_bounds__(256) void attn_sel(
    const float* __restrict__ q, const float* __restrict__ k,
    const float* __restrict__ v, float* __restrict__ agg)
{
  constexpr int KS_BYTES = 256 * D * 4;
  constexpr int MERGE_BYTES = 9216 + 9216 + 2304;  // mv + mi + sel = 20736
  constexpr int SMEM_BYTES = (KS_BYTES > MERGE_BYTES) ? KS_BYTES : MERGE_BYTES;
  __shared__ __align__(16) char smem[SMEM_BYTES];
  float* ks  = (float*)smem;               // [256*D], scan phase only
  float* mvS = (float*)smem;               // [4][576] aliases ks
  int*   miS = (int*)(smem + 9216);        // [4][576]
  int*   selS = (int*)(smem + 18432);      // [576]

  const int blk = blockIdx.x;
  const int b = blk >> 2;              // image
  const int t0 = (blk & 3) * 64;       // token base within image
  const int tid = threadIdx.x;
  const int tok = tid & 63;            // local token
  const int qt = tid >> 6;             // candidate quarter == wave == head
  const size_t base = (size_t)b * (256 * D);
  for (int idx = tid * 4; idx < 256 * D; idx += 1024)
    *(float4*)&ks[idx] = *(const float4*)&k[base + idx];
  float qr[D];
  {
    const float4* qrow = (const float4*)&q[base + (size_t)(t0 + tok) * D];
#pragma unroll
    for (int c4 = 0; c4 < D / 4; ++c4) {
      const float4 qv = qrow[c4];
      qr[4 * c4 + 0] = qv.x; qr[4 * c4 + 1] = qv.y;
      qr[4 * c4 + 2] = qv.z; qr[4 * c4 + 3] = qv.w;
    }
  }
  __syncthreads();

  float topv[9];
  int topi[9];
#pragma unroll
  for (int r = 0; r < 9; ++r) { topv[r] = -__builtin_inff(); topi[r] = 0; }

#pragma unroll 2
  for (int j = 0; j < 64; ++j) {
    const int m = qt * 64 + j;
    const float4* kr = (const float4*)&ks[m * D];
    float p0 = 0.f, p1 = 0.f, p2 = 0.f, p3 = 0.f;
#pragma unroll
    for (int g = 0; g < D / 16; ++g) {
      const float4 ka = kr[g * 4 + 0], kb = kr[g * 4 + 1];
      const float4 kc = kr[g * 4 + 2], kd = kr[g * 4 + 3];
      p0 += qr[g*16+ 0]*ka.x + qr[g*16+ 1]*ka.y + qr[g*16+ 2]*ka.z + qr[g*16+ 3]*ka.w;
      p1 += qr[g*16+ 4]*kb.x + qr[g*16+ 5]*kb.y + qr[g*16+ 6]*kb.z + qr[g*16+ 7]*kb.w;
      p2 += qr[g*16+ 8]*kc.x + qr[g*16+ 9]*kc.y + qr[g*16+10]*kc.z + qr[g*16+11]*kc.w;
      p3 += qr[g*16+12]*kd.x + qr[g*16+13]*kd.y + qr[g*16+14]*kd.z + qr[g*16+15]*kd.w;
    }
    const float s = (p0 + p1) + (p2 + p3);
    bool ci = s > topv[8];
#pragma unroll
    for (int i = 8; i >= 1; --i) {
      const bool cim1 = s > topv[i - 1];
      topv[i] = ci ? (cim1 ? topv[i - 1] : s) : topv[i];
      topi[i] = ci ? (cim1 ? topi[i - 1] : m) : topi[i];
      ci = cim1;
    }
    topv[0] = ci ? s : topv[0];
    topi[0] = ci ? m : topi[0];
  }
  __syncthreads();   // all waves done READING ks before aliased writes below
#pragma unroll
  for (int r = 0; r < 9; ++r) {
    mvS[qt * 576 + tok * 9 + r] = topv[r];
    miS[qt * 576 + tok * 9 + r] = topi[r];
  }
  __syncthreads();
  if (qt == 0) {   // wave 0 merges 36 -> 9 for its token
    float fv[9];
    int fi[9];
#pragma unroll
    for (int r = 0; r < 9; ++r) { fv[r] = -__builtin_inff(); fi[r] = 0; }
#pragma unroll
    for (int qq = 0; qq < 4; ++qq)
#pragma unroll
      for (int r = 0; r < 9; ++r) {
        const float s = mvS[qq * 576 + tok * 9 + r];
        const int ix = miS[qq * 576 + tok * 9 + r];
        bool ci = s > fv[8];
#pragma unroll
        for (int i = 8; i >= 1; --i) {
          const bool cim1 = s > fv[i - 1];
          fv[i] = ci ? (cim1 ? fv[i - 1] : s) : fv[i];
          fi[i] = ci ? (cim1 ? fi[i - 1] : ix) : fi[i];
          ci = cim1;
        }
        fv[0] = ci ? s : fv[0];
        fi[0] = ci ? ix : fi[0];
      }
#pragma unroll
    for (int r = 0; r < 9; ++r) selS[tok * 9 + r] = fi[r];
  }
  __syncthreads();

  // phases 2/3: this thread handles head hh = qt of token tok.
  const int hh = qt;
  const float scale = (DH == 4) ? 0.5f : 0.35355339059327373f;
  int sel9[9];
#pragma unroll
  for (int kk = 0; kk < 9; ++kk) sel9[kk] = selS[tok * 9 + kk];
  float lg9[9];
#pragma unroll
  for (int kk = 0; kk < 9; ++kk) {
    const float4* kr = (const float4*)&k[base + (size_t)sel9[kk] * D + hh * DH];
    float s = 0.f;
#pragma unroll
    for (int u = 0; u < DH / 4; ++u) {
      const float4 ka = kr[u];
      s += qr[hh*DH + u*4 + 0]*ka.x + qr[hh*DH + u*4 + 1]*ka.y +
           qr[hh*DH + u*4 + 2]*ka.z + qr[hh*DH + u*4 + 3]*ka.w;
    }
    lg9[kk] = s * scale;
  }
  float mx = lg9[0];
#pragma unroll
  for (int kk = 1; kk < 9; ++kk) mx = fmaxf(mx, lg9[kk]);
  float sum = 0.f;
#pragma unroll
  for (int kk = 0; kk < 9; ++kk) { lg9[kk] = __expf(lg9[kk] - mx); sum += lg9[kk]; }
  const float inv = 1.f / sum;
  float oacc[DH];
#pragma unroll
  for (int c = 0; c < DH; ++c) oacc[c] = 0.f;
#pragma unroll
  for (int kk = 0; kk < 9; ++kk) {
    const float4* vr = (const float4*)&v[base + (size_t)sel9[kk] * D + hh * DH];
    const float w = lg9[kk] * inv;
#pragma unroll
    for (int u = 0; u < DH / 4; ++u) {
      const float4 va = vr[u];
      oacc[u*4+0] += w * va.x; oacc[u*4+1] += w * va.y;
      oacc[u*4+2] += w * va.z; oacc[u*4+3] += w * va.w;
    }
  }
  float* o = &agg[base + (size_t)(t0 + tok) * D + hh * DH];
#pragma unroll
  for (int u = 0; u < DH / 4; ++u)
    *(float4*)&o[u * 4] = make_float4(oacc[u*4], oacc[u*4+1], oacc[u*4+2], oacc[u*4+3]);
}

// ---------------- proj1: t2 = [loc1|agg1] @ W1o + b1o, exact fp32 ----------
__global__ __launch_bounds__(256) void proj1(
    const float* __restrict__ loc1, const float* __restrict__ agg1,
    const float* __restrict__ w1o, const float* __restrict__ b1o,
    float* __restrict__ t2)
{
  const int tid = threadIdx.x;
  const int tok = blockIdx.x * 256 + tid;
  __shared__ float wS[32 * 64];   // 8 KB
  __shared__ float bS[64];
  for (int idx = tid * 4; idx < 2048; idx += 1024)
    *(float4*)&wS[idx] = *(const float4*)&w1o[idx];
  if (tid < 64) bS[tid] = b1o[tid];
  float cat[32];
#pragma unroll
  for (int c4 = 0; c4 < 4; ++c4) {
    const float4 l4 = *(const float4*)&loc1[(size_t)tok * 16 + c4 * 4];
    cat[4*c4+0] = l4.x; cat[4*c4+1] = l4.y; cat[4*c4+2] = l4.z; cat[4*c4+3] = l4.w;
    const float4 a4 = *(const float4*)&agg1[(size_t)tok * 16 + c4 * 4];
    cat[16+4*c4+0] = a4.x; cat[16+4*c4+1] = a4.y; cat[16+4*c4+2] = a4.z; cat[16+4*c4+3] = a4.w;
  }
  __syncthreads();
  float acc[64];
#pragma unroll
  for (int o = 0; o < 64; ++o) acc[o] = 0.f;
#pragma unroll 4
  for (int c = 0; c < 32; ++c) {
    const float cv = cat[c];
#pragma unroll
    for (int o4 = 0; o4 < 16; ++o4) {
      const float4 w4 = *(const float4*)&wS[c * 64 + o4 * 4];
      acc[o4*4+0] += cv * w4.x; acc[o4*4+1] += cv * w4.y;
      acc[o4*4+2] += cv * w4.z; acc[o4*4+3] += cv * w4.w;
    }
  }
  float* dst = t2 + (size_t)tok * 64;
#pragma unroll
  for (int o4 = 0; o4 < 16; ++o4)
    *(float4*)&dst[o4 * 4] = make_float4(acc[o4*4] + bS[o4*4], acc[o4*4+1] + bS[o4*4+1],
                                         acc[o4*4+2] + bS[o4*4+2], acc[o4*4+3] + bS[o4*4+3]);
}

// ---------------- K4: layer-2 q/k/v/local projections, exact fp32 ----------
__global__ __launch_bounds__(256) void k4_qkv2(
    const float* __restrict__ t2, const float* __restrict__ w2q,
    const float* __restrict__ w2k, const float* __restrict__ w2v,
    const float* __restrict__ w2c, const float* __restrict__ b2c,
    float* __restrict__ q2, float* __restrict__ k2,
    float* __restrict__ v2, float* __restrict__ loc2)
{
  const int blk = blockIdx.x;       // 1024 blocks x 64 tokens
  const int tid = threadIdx.x;
  __shared__ float t2S[64 * 68];    // 17.4 KB
  __shared__ float wS[4 * 2312];    // 37 KB
  __shared__ float bS[32];
  for (int idx = tid * 4; idx < 4096; idx += 1024) {
    const float4 vv = *(const float4*)&t2[(size_t)blk * 4096 + idx];
    *(float4*)&t2S[(idx >> 6) * 68 + (idx & 63)] = vv;
  }
  for (int idx = tid * 4; idx < 2048; idx += 1024) {
    const int c = idx >> 5, col = idx & 31;
    *(float4*)&wS[0 * 2312 + c * 36 + col] = *(const float4*)&w2q[idx];
    *(float4*)&wS[1 * 2312 + c * 36 + col] = *(const float4*)&w2k[idx];
    *(float4*)&wS[2 * 2312 + c * 36 + col] = *(const float4*)&w2v[idx];
    *(float4*)&wS[3 * 2312 + c * 36 + col] = *(const float4*)&w2c[idx];
  }
  if (tid < 32) bS[tid] = b2c[tid];
  __syncthreads();
  const int tq = tid >> 2, mat = tid & 3;
  const float* wm = &wS[mat * 2312];
  float acc[32];
#pragma unroll
  for (int e = 0; e < 32; ++e) acc[e] = 0.f;
#pragma unroll 4
  for (int c = 0; c < 64; ++c) {
    const float tv = t2S[tq * 68 + c];
#pragma unroll
    for (int o4 = 0; o4 < 8; ++o4) {
      const float4 w4 = *(const float4*)&wm[c * 36 + o4 * 4];
      acc[o4*4+0] += tv * w4.x; acc[o4*4+1] += tv * w4.y;
      acc[o4*4+2] += tv * w4.z; acc[o4*4+3] += tv * w4.w;
    }
  }
  if (mat == 3) {
#pragma unroll
    for (int e = 0; e < 32; ++e) acc[e] = fmaxf(acc[e] + bS[e], 0.f);
  }
  float* dst = (mat == 0) ? q2 : (mat == 1) ? k2 : (mat == 2) ? v2 : loc2;
  float* drow = dst + (size_t)(blk * 64 + tq) * 32;
#pragma unroll
  for (int o4 = 0; o4 < 8; ++o4)
    *(float4*)&drow[o4 * 4] = make_float4(acc[o4*4], acc[o4*4+1], acc[o4*4+2], acc[o4*4+3]);
}

// ---------------- proj2h: h = [loc2|agg2] @ W2o + b2o (bf16 MFMA) ----------
__global__ __launch_bounds__(256) void proj2h(
    const float* __restrict__ loc2, const float* __restrict__ agg2,
    const float* __restrict__ w2o, const float* __restrict__ b2o,
    __bf16* __restrict__ h)
{
  const int b = blockIdx.x;
  const int t = threadIdx.x;
  __shared__ __bf16 catB[256 * 72];   // 36.9 KB
  __shared__ __bf16 wB[128 * 72];     // 18.4 KB  [n][k]
  {  // stage W2o transposed to bf16 [n][k]
    const int n = t >> 1, khalf = t & 1;
    float wv[32];
#pragma unroll
    for (int j = 0; j < 32; ++j) wv[j] = w2o[(size_t)(khalf * 32 + j) * 128 + n];
#pragma unroll
    for (int j8 = 0; j8 < 4; ++j8)
      *(bf16x8*)&wB[n * 72 + khalf * 32 + j8 * 8] = pack8(&wv[j8 * 8]);
  }
  {  // stage cat row (loc2 | agg2) as bf16
    float lv[32];
#pragma unroll
    for (int c4 = 0; c4 < 8; ++c4) {
      const float4 x4 = *(const float4*)&loc2[(size_t)(b * 256 + t) * 32 + c4 * 4];
      lv[4*c4+0] = x4.x; lv[4*c4+1] = x4.y; lv[4*c4+2] = x4.z; lv[4*c4+3] = x4.w;
    }
#pragma unroll
    for (int c8 = 0; c8 < 4; ++c8)
      *(bf16x8*)&catB[t * 72 + c8 * 8] = pack8(&lv[c8 * 8]);
#pragma unroll
    for (int c4 = 0; c4 < 8; ++c4) {
      const float4 x4 = *(const float4*)&agg2[(size_t)(b * 256 + t) * 32 + c4 * 4];
      lv[4*c4+0] = x4.x; lv[4*c4+1] = x4.y; lv[4*c4+2] = x4.z; lv[4*c4+3] = x4.w;
    }
#pragma unroll
    for (int c8 = 0; c8 < 4; ++c8)
      *(bf16x8*)&catB[t * 72 + 32 + c8 * 8] = pack8(&lv[c8 * 8]);
  }
  __syncthreads();
  const int w = t >> 6, lane = t & 63, qd = lane >> 4, mcol = lane & 15;
#pragma unroll
  for (int nc = 0; nc < 2; ++nc) {
    floatx4 acc[4][4];
#pragma unroll
    for (int mi = 0; mi < 4; ++mi)
#pragma unroll
      for (int nj = 0; nj < 4; ++nj) acc[mi][nj] = (floatx4)0.f;
#pragma unroll
    for (int s = 0; s < 2; ++s) {
      bf16x8 af[4], bf[4];
#pragma unroll
      for (int mi = 0; mi < 4; ++mi)
        af[mi] = *(const bf16x8*)&catB[(w * 64 + mi * 16 + mcol) * 72 + s * 32 + qd * 8];
#pragma unroll
      for (int nj = 0; nj < 4; ++nj)
        bf[nj] = *(const bf16x8*)&wB[((nc * 4 + nj) * 16 + mcol) * 72 + s * 32 + qd * 8];
#pragma unroll
      for (int mi = 0; mi < 4; ++mi)
#pragma unroll
        for (int nj = 0; nj < 4; ++nj)
          acc[mi][nj] = __builtin_amdgcn_mfma_f32_16x16x32_bf16(af[mi], bf[nj], acc[mi][nj], 0, 0, 0);
    }
#pragma unroll
    for (int mi = 0; mi < 4; ++mi)
#pragma unroll
      for (int nj = 0; nj < 4; ++nj) {
        const int ch = (nc * 4 + nj) * 16 + mcol;
        const float bb = b2o[ch];
        const int cc = ch >> 2, si = (ch >> 1) & 1, sj = ch & 1;
#pragma unroll
        for (int r = 0; r < 4; ++r) {
          const int tok = w * 64 + mi * 16 + qd * 4 + r;
          const int i = tok >> 4, j = tok & 15;
          h[(size_t)b * 32768 + cc * 1024 + (2 * i + si) * 32 + (2 * j + sj)] =
              (__bf16)(acc[mi][nj][r] + bb);
        }
      }
  }
}

// ---------------- K7: fc1 GEMM bf16 MFMA, BK=256 ---------------------------
__global__ __launch_bounds__(256) void k7_fc1_gemm(
    const __bf16* __restrict__ A,  // h bf16 [256, 32768]
    const float* __restrict__ Bw,  // fc1_w fp32 [32768, 1024]
    float* __restrict__ part)      // [16][256][1024]
{
  __shared__ __bf16 Bs[32 * 264];  // [n][k] 16.9 KB, pad 264
  const int bn = blockIdx.x & 31;
  const int bk = blockIdx.x >> 5;
  const int n0 = bn * 32, k0 = bk * 2048;
  const int tid = threadIdx.x;
  const int n = tid & 31;          // staging column
  const int kg = tid >> 5;         // staging k-group (8 groups of 32)
  const int w = tid >> 6, lane = tid & 63;
  const int qd = lane >> 4, mcol = lane & 15;
  floatx4 acc[4][2];
#pragma unroll
  for (int mi = 0; mi < 4; ++mi)
#pragma unroll
    for (int ni = 0; ni < 2; ++ni) acc[mi][ni] = (floatx4)0.f;

  for (int it = 0; it < 8; ++it) {
    const int kk0 = k0 + it * 256;
    float bv[32];
    const float* bp = Bw + (size_t)(kk0 + kg * 32) * 1024 + n0 + n;
#pragma unroll
    for (int j = 0; j < 32; ++j) bv[j] = bp[(size_t)j * 1024];
    __syncthreads();   // previous iteration's Bs reads complete
#pragma unroll
    for (int j8 = 0; j8 < 4; ++j8)
      *(bf16x8*)&Bs[n * 264 + kg * 32 + j8 * 8] = pack8(&bv[j8 * 8]);
    __syncthreads();
#pragma unroll
    for (int s = 0; s < 8; ++s) {
      bf16x8 af[4], bf[2];
#pragma unroll
      for (int mi = 0; mi < 4; ++mi)
        af[mi] = *(const bf16x8*)(A + (size_t)(w * 64 + mi * 16 + mcol) * 32768
                                     + kk0 + s * 32 + qd * 8);
#pragma unroll
      for (int ni = 0; ni < 2; ++ni)
        bf[ni] = *(const bf16x8*)&Bs[(ni * 16 + mcol) * 264 + s * 32 + qd * 8];
#pragma unroll
      for (int mi = 0; mi < 4; ++mi)
#pragma unroll
        for (int ni = 0; ni < 2; ++ni)
          acc[mi][ni] = __builtin_amdgcn_mfma_f32_16x16x32_bf16(af[mi], bf[ni], acc[mi][ni], 0, 0, 0);
    }
  }
  float* P = part + (size_t)bk * 262144;
#pragma unroll
  for (int mi = 0; mi < 4; ++mi)
#pragma unroll
    for (int ni = 0; ni < 2; ++ni) {
      const int col = n0 + ni * 16 + mcol;
#pragma unroll
      for (int r = 0; r < 4; ++r) {
        const int row = w * 64 + mi * 16 + qd * 4 + r;
        P[(size_t)row * 1024 + col] = acc[mi][ni][r];
      }
    }
}

// ---------------- K7c+K8: splitK reduce + bias/relu + fc2 ------------------
__global__ __launch_bounds__(256) void k7c8_fc2(
    const float* __restrict__ part, const float* __restrict__ fc1b,
    const float* __restrict__ w2, const float* __restrict__ b2,
    float* __restrict__ out)
{
  const int b = blockIdx.x, t = threadIdx.x;
  const int col4 = t * 4;
  float4 s = make_float4(0.f, 0.f, 0.f, 0.f);
#pragma unroll
  for (int p = 0; p < 16; ++p) {
    const float4 x4 = *(const float4*)&part[(size_t)p * 262144 + (size_t)b * 1024 + col4];
    s.x += x4.x; s.y += x4.y; s.z += x4.z; s.w += x4.w;
  }
  const float4 bb = *(const float4*)&fc1b[col4];
  float a[4] = {fmaxf(s.x + bb.x, 0.f), fmaxf(s.y + bb.y, 0.f),
                fmaxf(s.z + bb.z, 0.f), fmaxf(s.w + bb.w, 0.f)};
  float acc[10];
#pragma unroll
  for (int o = 0; o < 10; ++o) acc[o] = 0.f;
#pragma unroll
  for (int i = 0; i < 4; ++i) {
    const float* wr = w2 + (size_t)(col4 + i) * 10;
#pragma unroll
    for (int o = 0; o < 10; ++o) acc[o] += a[i] * wr[o];
  }
  __shared__ float red[256][10];
#pragma unroll
  for (int o = 0; o < 10; ++o) red[t][o] = acc[o];
  __syncthreads();
  for (int st = 128; st > 0; st >>= 1) {
    if (t < st) {
#pragma unroll
      for (int o = 0; o < 10; ++o) red[t][o] += red[t + st][o];
    }
    __syncthreads();
  }
  if (t < 10) out[b * 10 + t] = red[0][t] + b2[t];
}

// ---------------------------------------------------------------------------
extern "C" void kernel_launch(void* const* d_in, const int* in_sizes, int n_in,
                              void* d_out, int out_size, void* d_ws, size_t ws_size,
                              hipStream_t stream)
{
  const float* x    = (const float*)d_in[0];
  const float* w1c  = (const float*)d_in[1];
  const float* b1c  = (const float*)d_in[2];
  const float* w1q  = (const float*)d_in[3];
  const float* w1k  = (const float*)d_in[4];
  const float* w1v  = (const float*)d_in[5];
  const float* w1o  = (const float*)d_in[6];
  const float* b1o  = (const float*)d_in[7];
  const float* w2c  = (const float*)d_in[8];
  const float* b2c  = (const float*)d_in[9];
  const float* w2q  = (const float*)d_in[10];
  const float* w2k  = (const float*)d_in[11];
  const float* w2v  = (const float*)d_in[12];
  const float* w2o  = (const float*)d_in[13];
  const float* b2o  = (const float*)d_in[14];
  const float* fc1w = (const float*)d_in[15];
  const float* fc1b = (const float*)d_in[16];
  const float* fc2w = (const float*)d_in[17];
  const float* fc2b = (const float*)d_in[18];
  float* out = (float*)d_out;
  float* ws = (float*)d_ws;

  float* q1   = ws + OQ1;
  float* k1   = ws + OK1;
  float* v1   = ws + OV1;
  float* loc1 = ws + OL1;
  float* agg1 = ws + OA1;
  float* t2   = ws + OT2;
  float* q2   = ws + OQ2;
  float* k2   = ws + OK2;
  float* v2   = ws + OV2;
  float* loc2 = ws + OL2;
  float* agg2 = ws + OA2;
  __bf16* h   = (__bf16*)(ws + OH);
  float* prt  = ws + OPART;

  k1_qkv1<<<16384, 256, 0, stream>>>(x, w1q, w1k, w1v, w1c, b1c, q1, k1, v1, loc1);
  attn_sel<16, 4, 4><<<1024, 256, 0, stream>>>(q1, k1, v1, agg1);
  proj1<<<256, 256, 0, stream>>>(loc1, agg1, w1o, b1o, t2);
  k4_qkv2<<<1024, 256, 0, stream>>>(t2, w2q, w2k, w2v, w2c, b2c, q2, k2, v2, loc2);
  attn_sel<32, 8, 4><<<1024, 256, 0, stream>>>(q2, k2, v2, agg2);
  proj2h<<<256, 256, 0, stream>>>(loc2, agg2, w2o, b2o, h);
  k7_fc1_gemm<<<512, 256, 0, stream>>>(h, fc1w, prt);
  k7c8_fc2<<<256, 256, 0, stream>>>(prt, fc1b, fc2w, fc2b, out);
}